// Round 4
// baseline (256.040 us; speedup 1.0000x reference)
//
#include <hip/hip_runtime.h>
#include <math.h>

#define NC   1000      // classes
#define DD   4096      // dense dim
#define BB   8192      // batch

#define MAIN_BLOCKS (NC * 4)           // 4 chunks of 1024 d's per class
#define CE_BLOCKS   (BB / 4)           // 4 waves/block, 1 sample/wave
#define MAXN 144                       // max samples per class (~Poisson(8.2)) + pad room
#define NSLOT 32                       // loss accumulator slots (contention spread)
#define LN2  0.69314718055994531f

// ws: 0: loss1 double[32] | 256: loss2 double[32]   (memset 512 B)

// full (unmasked) accumulate. log2-space BCE: bceB accumulates log2(1+e),
// scaled by ln2 ONCE per thread at the end (saves 1 VALU op per element in
// a 3-transcendental hot path).
#define ACC1(xv, yv, acc)                                                     \
    {                                                                         \
        float e = __expf(-fabsf(xv));                                         \
        float inv = __builtin_amdgcn_rcpf(1.f + e);                           \
        acc += (xv >= 0.f) ? inv : e * inv;                                   \
        bceA += fmaxf(xv, 0.f) - xv * yv;                                     \
        bceB += __log2f(1.f + e);                                             \
    }

// masked accumulate (tail batch only): w in {0,1}
#define ACC1W(xv, yv, acc, w)                                                 \
    {                                                                         \
        float e = __expf(-fabsf(xv));                                         \
        float inv = __builtin_amdgcn_rcpf(1.f + e);                           \
        float sg = (xv >= 0.f) ? inv : e * inv;                               \
        acc += w * sg;                                                        \
        bceA += w * (fmaxf(xv, 0.f) - xv * yv);                               \
        bceB += w * __log2f(1.f + e);                                         \
    }

// EMPIRICAL OCCUPANCY LAW (R0-R3 counters): waves/CU ~= 750/VGPR.
//   R0: VGPR=32 -> occ 70% (22 w/CU); R3: VGPR=60 -> occ 39% (12.5 w/CU).
// MLP depth and TLP trade through the same register budget. Batch-4 sits
// at the sweet spot: xa[4]=16 + y=4 + acc=6 + offsets/misc ~= 44 VGPR
// -> ~17 waves/CU with 4-deep MLP. Padding waste E[slots] 12.5 -> 10.2.
__global__ __launch_bounds__(256, 4) void main_k(const float* __restrict__ dense_out,
                                                 const int*   __restrict__ target,
                                                 const float* __restrict__ dense_labels,
                                                 float* __restrict__ out,
                                                 double* __restrict__ loss2) {
    int bx = blockIdx.x;
    int t  = threadIdx.x;
    int wave = t >> 6;
    int lane = t & 63;

    __shared__ int   sidx[MAXN];
    __shared__ int   s_n;
    __shared__ float red[4];

    int c     = bx >> 2;
    int chunk = bx & 3;
    int d     = chunk * 1024 + (t << 2);

    if (t == 0) s_n = 0;
    __syncthreads();

    // 32-bit float4 indexing: max offset 8191*1024*16B = 134 MB < 2^31,
    // so addresses are SGPR-base + one 32-bit VGPR offset
    const float4* dp4 = (const float4*)(dense_out + d);
    float4 y = *(const float4*)(dense_labels + (size_t)c * DD + d);

    // scan all targets (32 KB, L1/L2-resident) and compact class-c samples
    const int4* tp = (const int4*)target;
    #pragma unroll
    for (int k = 0; k < 8; ++k) {
        int4 v = tp[k * 256 + t];
        int s0 = (k * 256 + t) * 4;
        if (v.x == c) { int p = atomicAdd(&s_n, 1); sidx[p] = s0;     }
        if (v.y == c) { int p = atomicAdd(&s_n, 1); sidx[p] = s0 + 1; }
        if (v.z == c) { int p = atomicAdd(&s_n, 1); sidx[p] = s0 + 2; }
        if (v.w == c) { int p = atomicAdd(&s_n, 1); sidx[p] = s0 + 3; }
    }
    __syncthreads();
    int n  = s_n;
    int n4 = (n + 3) & ~3;
    // pad sidx to a multiple of 4 with a valid duplicate index so every
    // batch's 4 gather loads are UNCONDITIONAL (4-deep MLP per wave)
    if (t < n4 - n) sidx[n + t] = sidx[0];
    __syncthreads();

    float a0 = 0.f, a1 = 0.f, a2 = 0.f, a3 = 0.f, bceA = 0.f, bceB = 0.f;

    for (int base = 0; base < n4; base += 4) {
        float4 xa[4];
        #pragma unroll
        for (int j = 0; j < 4; ++j)
            xa[j] = dp4[sidx[base + j] * (DD / 4)];

        if (base + 4 <= n) {
            // full batch, no masking (wave-uniform branch)
            #pragma unroll
            for (int j = 0; j < 4; ++j) {
                ACC1(xa[j].x, y.x, a0) ACC1(xa[j].y, y.y, a1)
                ACC1(xa[j].z, y.z, a2) ACC1(xa[j].w, y.w, a3)
            }
        } else {
            // tail batch: mask padded elements with w in {0,1}
            #pragma unroll
            for (int j = 0; j < 4; ++j) {
                float w = (base + j < n) ? 1.f : 0.f;
                ACC1W(xa[j].x, y.x, a0, w) ACC1W(xa[j].y, y.y, a1, w)
                ACC1W(xa[j].z, y.z, a2, w) ACC1W(xa[j].w, y.w, a3, w)
            }
        }
    }

    // out+1 is the [NC,DD] segment-sum (4B-aligned only -> dword stores)
    float* p = out + 1 + (size_t)c * DD + d;
    p[0] = a0; p[1] = a1; p[2] = a2; p[3] = a3;

    if (chunk == 0 && t == 0) out[1 + (size_t)NC * DD + c] = (float)n;

    float bce = bceA + LN2 * bceB;
    #pragma unroll
    for (int o2 = 32; o2 > 0; o2 >>= 1) bce += __shfl_xor(bce, o2);
    if (lane == 0) red[wave] = bce;
    __syncthreads();
    if (t == 0)
        atomicAdd(&loss2[bx & (NSLOT - 1)],
                  (double)(red[0] + red[1] + red[2] + red[3]));
}

__global__ __launch_bounds__(256) void ce_k(const float* __restrict__ logits,
                                            const int*   __restrict__ target,
                                            double* __restrict__ loss1) {
    int bx = blockIdx.x;
    int t  = threadIdx.x;
    int wave = t >> 6;
    int lane = t & 63;

    __shared__ float red[4];

    int i = bx * 4 + wave;
    const float* row = logits + (size_t)i * NC;
    int j0 = lane * 4;

    float4 r0 = *(const float4*)(row + j0);
    float4 r1 = *(const float4*)(row + j0 + 256);
    float4 r2 = *(const float4*)(row + j0 + 512);
    float4 r3;
    if (j0 + 768 < NC) r3 = *(const float4*)(row + j0 + 768);
    else r3 = make_float4(-INFINITY, -INFINITY, -INFINITY, -INFINITY);
    float tl = row[target[i]];

    float mx = fmaxf(fmaxf(fmaxf(r0.x, r0.y), fmaxf(r0.z, r0.w)),
                     fmaxf(fmaxf(r1.x, r1.y), fmaxf(r1.z, r1.w)));
    mx = fmaxf(mx, fmaxf(fmaxf(r2.x, r2.y), fmaxf(r2.z, r2.w)));
    mx = fmaxf(mx, fmaxf(fmaxf(r3.x, r3.y), fmaxf(r3.z, r3.w)));
    #pragma unroll
    for (int o = 32; o > 0; o >>= 1) mx = fmaxf(mx, __shfl_xor(mx, o));

    float s = __expf(r0.x - mx) + __expf(r0.y - mx) + __expf(r0.z - mx) + __expf(r0.w - mx)
            + __expf(r1.x - mx) + __expf(r1.y - mx) + __expf(r1.z - mx) + __expf(r1.w - mx)
            + __expf(r2.x - mx) + __expf(r2.y - mx) + __expf(r2.z - mx) + __expf(r2.w - mx)
            + __expf(r3.x - mx) + __expf(r3.y - mx) + __expf(r3.z - mx) + __expf(r3.w - mx);
    #pragma unroll
    for (int o = 32; o > 0; o >>= 1) s += __shfl_xor(s, o);

    if (lane == 0) red[wave] = -(tl - mx - __logf(s));
    __syncthreads();
    if (t == 0)
        atomicAdd(&loss1[bx & (NSLOT - 1)],
                  (double)(red[0] + red[1] + red[2] + red[3]));
}

__global__ void fin_k(const double* __restrict__ loss1,
                      const double* __restrict__ loss2,
                      float* __restrict__ out) {
    double l1 = 0.0, l2 = 0.0;
    #pragma unroll
    for (int i = 0; i < NSLOT; ++i) { l1 += loss1[i]; l2 += loss2[i]; }
    out[0] = (float)(0.5 * (l1 / (double)BB) +
                     0.5 * (l2 / ((double)BB * (double)DD)));
}

extern "C" void kernel_launch(void* const* d_in, const int* in_sizes, int n_in,
                              void* d_out, int out_size, void* d_ws, size_t ws_size,
                              hipStream_t stream) {
    const float* logits       = (const float*)d_in[0];
    const float* dense_out    = (const float*)d_in[1];
    const int*   target       = (const int*)d_in[2];
    const float* dense_labels = (const float*)d_in[3];
    float* out = (float*)d_out;

    char* ws = (char*)d_ws;
    double* loss1 = (double*)(ws + 0);
    double* loss2 = (double*)(ws + 256);

    hipMemsetAsync(d_ws, 0, 512, stream);

    main_k<<<MAIN_BLOCKS, 256, 0, stream>>>(dense_out, target, dense_labels,
                                            out, loss2);
    ce_k<<<CE_BLOCKS, 256, 0, stream>>>(logits, target, loss1);
    fin_k<<<1, 1, 0, stream>>>(loss1, loss2, out);
}

// Round 6
// 255.851 us; speedup vs baseline: 1.0007x; 1.0007x over previous
//
#include <hip/hip_runtime.h>
#include <math.h>

#define NC   1000      // classes
#define DD   4096      // dense dim
#define BB   8192      // batch

#define MAIN_BLOCKS (NC * 2)           // 2 chunks of 2048 d's per class
#define CE_BLOCKS   (BB / 4)           // 4 waves/block, 1 sample/wave
#define TOT_BLOCKS  (MAIN_BLOCKS + CE_BLOCKS)   // 4048
#define MAXN 144                       // max samples per class (~Poisson(8.2)) + pad room
#define NSLOT 32                       // loss accumulator slots (contention spread)
#define LN2  0.69314718055994531f

// ws: 0: loss1 double[32] | 256: loss2 double[32]   (memset 512 B)

// per-element accumulate. y is HOISTED out of the loop (sum x*y = y*sum x),
// so the loop tracks: aAcc = sum sigmoid, sAcc = sum x, bceA = sum max(x,0),
// bceB = sum log2(1+e). bce assembled in the epilogue with one y load.
#define ACCX(xv, aAcc, sAcc)                                                  \
    {                                                                         \
        float e   = __expf(-fabsf(xv));                                       \
        float p1  = 1.f + e;                                                  \
        float inv = __builtin_amdgcn_rcpf(p1);                                \
        aAcc += (xv >= 0.f) ? inv : e * inv;                                  \
        sAcc += xv;                                                           \
        bceA += fmaxf(xv, 0.f);                                               \
        bceB += __log2f(p1);                                                  \
    }

// EMPIRICAL OCCUPANCY LAW (R0-R3): waves/CU ~= 750/VGPR; MLP depth and TLP
// trade through one register budget. Batch-2 x 2-half: 16 data VGPR (4-deep
// MLP) + 18 accumulators ~= 55 < 64 cap at (256,4).
// Fixed-vs-variable: per-block fixed cost (scan/barriers/epilogue) ~= ACC
// compute at 4000 blocks; 2048-d chunks halve block count -> halve fixed.
__global__ __launch_bounds__(256, 4) void fused_k(const float* __restrict__ logits,
                                                  const float* __restrict__ dense_out,
                                                  const int*   __restrict__ target,
                                                  const float* __restrict__ dense_labels,
                                                  float* __restrict__ out,
                                                  double* __restrict__ loss1,
                                                  double* __restrict__ loss2) {
    int bx = blockIdx.x;
    int t  = threadIdx.x;
    int wave = t >> 6;
    int lane = t & 63;

    __shared__ int   sidx[MAXN];
    __shared__ int   s_n;
    __shared__ float red[4];

    // interleave: even bx < 4000 are main blocks, everything else CE.
    // CE blocks run concurrently with main blocks across the whole dispatch,
    // filling main-path memory-latency gaps (the R4 split serialized them).
    bool is_main = ((bx & 1) == 0) && (bx < 2 * MAIN_BLOCKS);

    if (is_main) {
        // ------------- main path: one (class, 2048-d chunk) per block ------
        int mb    = bx >> 1;            // 0..1999
        int c     = mb >> 1;
        int chunk = mb & 1;
        int dbase = chunk * 2048 + (t << 2);  // floats; this thread covers
                                              // [dbase, dbase+4) and [dbase+1024, dbase+1028)

        if (t == 0) s_n = 0;
        __syncthreads();

        // 32-bit float4 indexing off a wave-uniform-ish base: row idx ->
        // offset idx*1024 (f4 units), +256 for the upper half. Max offset
        // 8191*1024+256 < 2^31.
        const float4* dpA = (const float4*)(dense_out + dbase);

        // scan all targets (32 KB, L1/L2-resident) and compact class-c samples
        const int4* tp = (const int4*)target;
        #pragma unroll
        for (int k = 0; k < 8; ++k) {
            int4 v = tp[k * 256 + t];
            int s0 = (k * 256 + t) * 4;
            if (v.x == c) { int p = atomicAdd(&s_n, 1); sidx[p] = s0;     }
            if (v.y == c) { int p = atomicAdd(&s_n, 1); sidx[p] = s0 + 1; }
            if (v.z == c) { int p = atomicAdd(&s_n, 1); sidx[p] = s0 + 2; }
            if (v.w == c) { int p = atomicAdd(&s_n, 1); sidx[p] = s0 + 3; }
        }
        __syncthreads();
        int n  = s_n;
        int n2 = (n + 1) & ~1;
        // pad to even with a duplicate so both samples' loads are
        // unconditional; the tail batch SKIPS the padded sample entirely
        // (wave-uniform branch), so there is no masked-math path at all.
        if (t == 0 && n2 != n) sidx[n] = sidx[0];
        __syncthreads();

        float a0 = 0.f, a1 = 0.f, a2 = 0.f, a3 = 0.f;
        float a4 = 0.f, a5 = 0.f, a6 = 0.f, a7 = 0.f;
        float s0 = 0.f, s1 = 0.f, s2 = 0.f, s3 = 0.f;
        float s4 = 0.f, s5 = 0.f, s6 = 0.f, s7 = 0.f;
        float bceA = 0.f, bceB = 0.f;

        for (int base = 0; base < n2; base += 2) {
            int oA = sidx[base]     << 10;   // *1024 f4 units = row stride
            int oB = sidx[base + 1] << 10;
            // 4 unconditional loads issued back-to-back: 4-deep MLP
            float4 xa0 = dpA[oA];
            float4 xa1 = dpA[oA + 256];
            float4 xb0 = dpA[oB];
            float4 xb1 = dpA[oB + 256];

            ACCX(xa0.x, a0, s0) ACCX(xa0.y, a1, s1)
            ACCX(xa0.z, a2, s2) ACCX(xa0.w, a3, s3)
            ACCX(xa1.x, a4, s4) ACCX(xa1.y, a5, s5)
            ACCX(xa1.z, a6, s6) ACCX(xa1.w, a7, s7)
            if (base + 1 < n) {   // false only for the tail's padded sample
                ACCX(xb0.x, a0, s0) ACCX(xb0.y, a1, s1)
                ACCX(xb0.z, a2, s2) ACCX(xb0.w, a3, s3)
                ACCX(xb1.x, a4, s4) ACCX(xb1.y, a5, s5)
                ACCX(xb1.z, a6, s6) ACCX(xb1.w, a7, s7)
            }
        }

        // epilogue: y enters here only (y-hoist). bce = sum[max + ln2*log2]
        // - sum_d y_d * sx_d
        const float4* yp = (const float4*)(dense_labels + (size_t)c * DD + dbase);
        float4 y0 = yp[0];
        float4 y1 = yp[256];
        float bce = bceA + LN2 * bceB
                  - (y0.x * s0 + y0.y * s1 + y0.z * s2 + y0.w * s3
                   + y1.x * s4 + y1.y * s5 + y1.z * s6 + y1.w * s7);

        // out+1 is the [NC,DD] segment-sum (4B-aligned only -> dword stores)
        float* p = out + 1 + (size_t)c * DD + dbase;
        p[0] = a0; p[1] = a1; p[2] = a2; p[3] = a3;
        p[1024] = a4; p[1025] = a5; p[1026] = a6; p[1027] = a7;

        if (chunk == 0 && t == 0) out[1 + (size_t)NC * DD + c] = (float)n;

        #pragma unroll
        for (int o2 = 32; o2 > 0; o2 >>= 1) bce += __shfl_xor(bce, o2);
        if (lane == 0) red[wave] = bce;
        __syncthreads();
        if (t == 0)
            atomicAdd(&loss2[mb & (NSLOT - 1)],
                      (double)(red[0] + red[1] + red[2] + red[3]));
    } else {
        // ------------- CE path: 4 waves/block, one sample per wave ---------
        int ce_i = (bx < 2 * MAIN_BLOCKS) ? (bx >> 1) : (bx - MAIN_BLOCKS);
        int i = ce_i * 4 + wave;
        const float* row = logits + (size_t)i * NC;
        int j0 = lane * 4;

        float4 r0 = *(const float4*)(row + j0);
        float4 r1 = *(const float4*)(row + j0 + 256);
        float4 r2 = *(const float4*)(row + j0 + 512);
        float4 r3;
        if (j0 + 768 < NC) r3 = *(const float4*)(row + j0 + 768);
        else r3 = make_float4(-INFINITY, -INFINITY, -INFINITY, -INFINITY);
        float tl = row[target[i]];

        float mx = fmaxf(fmaxf(fmaxf(r0.x, r0.y), fmaxf(r0.z, r0.w)),
                         fmaxf(fmaxf(r1.x, r1.y), fmaxf(r1.z, r1.w)));
        mx = fmaxf(mx, fmaxf(fmaxf(r2.x, r2.y), fmaxf(r2.z, r2.w)));
        mx = fmaxf(mx, fmaxf(fmaxf(r3.x, r3.y), fmaxf(r3.z, r3.w)));
        #pragma unroll
        for (int o = 32; o > 0; o >>= 1) mx = fmaxf(mx, __shfl_xor(mx, o));

        float s = __expf(r0.x - mx) + __expf(r0.y - mx) + __expf(r0.z - mx) + __expf(r0.w - mx)
                + __expf(r1.x - mx) + __expf(r1.y - mx) + __expf(r1.z - mx) + __expf(r1.w - mx)
                + __expf(r2.x - mx) + __expf(r2.y - mx) + __expf(r2.z - mx) + __expf(r2.w - mx)
                + __expf(r3.x - mx) + __expf(r3.y - mx) + __expf(r3.z - mx) + __expf(r3.w - mx);
        #pragma unroll
        for (int o = 32; o > 0; o >>= 1) s += __shfl_xor(s, o);

        if (lane == 0) red[wave] = -(tl - mx - __logf(s));
        __syncthreads();
        if (t == 0)
            atomicAdd(&loss1[ce_i & (NSLOT - 1)],
                      (double)(red[0] + red[1] + red[2] + red[3]));
    }
}

__global__ void fin_k(const double* __restrict__ loss1,
                      const double* __restrict__ loss2,
                      float* __restrict__ out) {
    double l1 = 0.0, l2 = 0.0;
    #pragma unroll
    for (int i = 0; i < NSLOT; ++i) { l1 += loss1[i]; l2 += loss2[i]; }
    out[0] = (float)(0.5 * (l1 / (double)BB) +
                     0.5 * (l2 / ((double)BB * (double)DD)));
}

extern "C" void kernel_launch(void* const* d_in, const int* in_sizes, int n_in,
                              void* d_out, int out_size, void* d_ws, size_t ws_size,
                              hipStream_t stream) {
    const float* logits       = (const float*)d_in[0];
    const float* dense_out    = (const float*)d_in[1];
    const int*   target       = (const int*)d_in[2];
    const float* dense_labels = (const float*)d_in[3];
    float* out = (float*)d_out;

    char* ws = (char*)d_ws;
    double* loss1 = (double*)(ws + 0);
    double* loss2 = (double*)(ws + 256);

    hipMemsetAsync(d_ws, 0, 512, stream);

    fused_k<<<TOT_BLOCKS, 256, 0, stream>>>(logits, dense_out, target,
                                            dense_labels, out, loss1, loss2);
    fin_k<<<1, 1, 0, stream>>>(loss1, loss2, out);
}